// Round 1
// baseline (135.168 us; speedup 1.0000x reference)
//
#include <hip/hip_runtime.h>
#include <hip/hip_bf16.h>
#include <math.h>

// Problem constants (from reference):
//   logits [8,19,256,512] f32, targets [8,256,512] int
//   R=20 truncated EDT, loss = mean_b sum_c mean_hw probs*sdf
#define NCLS 19
#define BB   8
#define HH   256
#define WW   512
#define DCAP 21u      // capped 1D distance; 21^2=441 > 400 saturates like INF
#define CAP2 400u     // R^2

static __device__ __forceinline__ unsigned umin32(unsigned a, unsigned b) { return a < b ? a : b; }

// ---------------------------------------------------------------------------
// Kernel A: vertical pass. For each (b, w) column and each class c, compute
// vneg[b][c][h][w] = min(|dh|) s.t. target[h+dh][w]==c, capped at 21.
// Columns split into 16-row segments (prescan 21 rows each side) for occupancy.
// ---------------------------------------------------------------------------
__global__ __launch_bounds__(256)
void kA_vert(const int* __restrict__ targ, unsigned char* __restrict__ vneg) {
    const int ROWS = 16;                       // rows per segment (H/SEG, SEG=16)
    int gid = blockIdx.x * 256 + threadIdx.x;  // 4096 cols * 16 segs = 65536
    int col = gid & 4095;                      // lanes get adjacent w -> coalesced
    int seg = gid >> 12;
    int b = col >> 9;
    int w = col & 511;
    int h0 = seg * ROWS;

    // down scan (top -> bottom): distance to nearest c at row' <= h
    unsigned d[NCLS];
#pragma unroll
    for (int c = 0; c < NCLS; ++c) d[c] = DCAP;
    int hstart = h0 - (int)DCAP; if (hstart < 0) hstart = 0;
    for (int hh = hstart; hh < h0 + ROWS; ++hh) {
        int t = targ[(b * HH + hh) * WW + w];
#pragma unroll
        for (int c = 0; c < NCLS; ++c) {
            unsigned nd = umin32(d[c] + 1u, DCAP);
            d[c] = (t == c) ? 0u : nd;
        }
        if (hh >= h0) {
#pragma unroll
            for (int c = 0; c < NCLS; ++c)
                vneg[((size_t)(b * NCLS + c) * HH + hh) * WW + w] = (unsigned char)d[c];
        }
    }

    // up scan (bottom -> top): min with distance to nearest c at row' >= h
    unsigned u[NCLS];
#pragma unroll
    for (int c = 0; c < NCLS; ++c) u[c] = DCAP;
    int hend = h0 + ROWS - 1 + (int)DCAP; if (hend > HH - 1) hend = HH - 1;
    for (int hh = hend; hh >= h0; --hh) {
        int t = targ[(b * HH + hh) * WW + w];
#pragma unroll
        for (int c = 0; c < NCLS; ++c) {
            unsigned nu = umin32(u[c] + 1u, DCAP);
            u[c] = (t == c) ? 0u : nu;
        }
        if (hh < h0 + ROWS) {
#pragma unroll
            for (int c = 0; c < NCLS; ++c) {
                size_t idx = ((size_t)(b * NCLS + c) * HH + hh) * WW + w;
                unsigned char dv = vneg[idx];   // same thread wrote it (down scan)
                vneg[idx] = (unsigned char)umin32(dv, u[c]);
            }
        }
    }
}

// ---------------------------------------------------------------------------
// Kernel B: per image row (b,h). Stage v^2 per class into LDS (halo=441),
// horizontal 41-tap min-plus per class, fused softmax + loss accumulation.
// sdf(c!=t0) = +sqrt(min(nd2[c],400))/20 ; sdf(t0) = -sqrt(min(m2,400))/20
// where m2 = min_{c!=t0} nd2[c]  (posdist identity).
// Deterministic: fixed-point (2^36) s64 atomic per workgroup.
// ---------------------------------------------------------------------------
#define LROW 552   // 512 + 2*20 halo

__global__ __launch_bounds__(256)
void kB_main(const float* __restrict__ logits, const int* __restrict__ targ,
             const unsigned char* __restrict__ vneg,
             unsigned long long* __restrict__ acc) {
    __shared__ unsigned int lds[NCLS * LROW];
    __shared__ float red[256];
    int bh = blockIdx.x;      // 0..B*H-1
    int b = bh >> 8;
    int h = bh & 255;
    int tid = threadIdx.x;

    // halos: v^2 = 441 (out-of-bounds acts like INF after the 400 cap)
    for (int i = tid; i < NCLS * 40; i += 256) {
        int c = i / 40; int k = i % 40;
        int idx = (k < 20) ? k : (512 + 20 + (k - 20));
        lds[c * LROW + idx] = DCAP * DCAP;
    }
    // main: read u8 vertical distances (4 at a time), square into u32 LDS
    const unsigned int* vn32 = (const unsigned int*)vneg;
    for (int i = tid; i < NCLS * (WW / 4); i += 256) {
        int c = i >> 7;        // /128
        int w4 = i & 127;
        unsigned int v4 = vn32[((size_t)(b * NCLS + c) * HH + h) * (WW / 4) + w4];
        unsigned int base = c * LROW + 20 + w4 * 4;
#pragma unroll
        for (int k = 0; k < 4; ++k) {
            unsigned int v = (v4 >> (8 * k)) & 0xffu;
            lds[base + k] = v * v;
        }
    }
    __syncthreads();

    int w0 = tid * 2;  // each thread: 2 adjacent pixels, shared 42-word window
    int t0 = targ[(b * HH + h) * WW + w0];
    int t1 = targ[(b * HH + h) * WW + w0 + 1];

    float num0 = 0.f, num1 = 0.f, den0 = 0.f, den1 = 0.f;
    float et0 = 0.f, et1 = 0.f;
    unsigned m2_0 = 1u << 30, m2_1 = 1u << 30;

#pragma unroll 1
    for (int c = 0; c < NCLS; ++c) {
        unsigned win[42];
        const unsigned int* lc = &lds[c * LROW + w0];
#pragma unroll
        for (int j = 0; j < 42; ++j) win[j] = lc[j];

        unsigned nd0 = 1u << 30, nd1 = 1u << 30;
#pragma unroll
        for (int j = 0; j <= 40; ++j)
            nd0 = umin32(nd0, win[j] + (unsigned)((j - 20) * (j - 20)));
#pragma unroll
        for (int j = 1; j <= 41; ++j)
            nd1 = umin32(nd1, win[j] + (unsigned)((j - 21) * (j - 21)));

        float2 l2 = *(const float2*)&logits[(((size_t)b * NCLS + c) * HH + h) * WW + w0];
        float e0 = expf(l2.x), e1 = expf(l2.y);   // no max-sub needed: |logit|~3
        den0 += e0; den1 += e1;
        bool is0 = (c == t0), is1 = (c == t1);
        float s0 = sqrtf((float)umin32(nd0, CAP2));
        float s1 = sqrtf((float)umin32(nd1, CAP2));
        num0 += is0 ? 0.f : e0 * s0;
        num1 += is1 ? 0.f : e1 * s1;
        et0 = is0 ? e0 : et0;
        et1 = is1 ? e1 : et1;
        m2_0 = umin32(m2_0, is0 ? (1u << 30) : nd0);
        m2_1 = umin32(m2_1, is1 ? (1u << 30) : nd1);
    }
    num0 -= et0 * sqrtf((float)umin32(m2_0, CAP2));
    num1 -= et1 * sqrtf((float)umin32(m2_1, CAP2));

    red[tid] = num0 / den0 + num1 / den1;   // still needs /20 (done at the end)
    __syncthreads();
    for (int s = 128; s > 0; s >>= 1) {
        if (tid < s) red[tid] += red[tid + s];
        __syncthreads();
    }
    if (tid == 0) {
        // fixed-point 2^36, /20 folded in; integer atomics => bit-deterministic
        double q = (double)red[0] * (68719476736.0 / 20.0);
        long long iv = (long long)q;
        atomicAdd(acc, (unsigned long long)iv);
    }
}

__global__ void kC_final(const unsigned long long* __restrict__ acc,
                         float* __restrict__ out) {
    long long iv = (long long)*acc;
    double v = (double)iv / 68719476736.0;
    out[0] = (float)(v / (double)((size_t)BB * HH * WW));
}

extern "C" void kernel_launch(void* const* d_in, const int* in_sizes, int n_in,
                              void* d_out, int out_size, void* d_ws, size_t ws_size,
                              hipStream_t stream) {
    const float* logits = (const float*)d_in[0];
    const int* targ = (const int*)d_in[1];
    unsigned char* wsb = (unsigned char*)d_ws;
    unsigned long long* acc = (unsigned long long*)wsb;       // [0,8)
    unsigned char* vneg = wsb + 64;                           // 19.9 MB u8

    hipMemsetAsync(d_ws, 0, 64, stream);
    kA_vert<<<256, 256, 0, stream>>>(targ, vneg);             // 65536 threads
    kB_main<<<BB * HH, 256, 0, stream>>>(logits, targ, vneg, acc);
    kC_final<<<1, 1, 0, stream>>>(acc, (float*)d_out);
}

// Round 3
// 93.970 us; speedup vs baseline: 1.4384x; 1.4384x over previous
//
#include <hip/hip_runtime.h>
#include <hip/hip_bf16.h>
#include <math.h>

// logits [8,19,256,512] f32, targets [8,256,512] int32
// R=20 truncated EDT, loss = mean_b sum_c mean_hw probs*sdf
#define NCLS 19
#define BB   8
#define HH   256
#define WW   512
#define DCAP 21u      // capped 1D distance; 21^2=441 > 400 saturates like INF
#define CAP2 400u     // R^2
#define SEG  4        // rows per kA segment

typedef unsigned short u16x2 __attribute__((ext_vector_type(2)));

static __device__ __forceinline__ unsigned umin32(unsigned a, unsigned b) { return a < b ? a : b; }
static __device__ __forceinline__ float fsqrt_fast(float x) { return __builtin_amdgcn_sqrtf(x); }

// ---------------------------------------------------------------------------
// Kernel A: vertical pass. vneg[b][c][h][w] = min |dh| with targ[h+dh][w]==c,
// capped at 21. 4-row segments, down results packed in registers (no RMW).
// 262144 threads -> 16 waves/CU.
// ---------------------------------------------------------------------------
__global__ __launch_bounds__(256)
void kA_vert(const int* __restrict__ targ, unsigned char* __restrict__ vneg) {
    int gid = blockIdx.x * 256 + threadIdx.x;  // 4096 cols * 64 segs
    int col = gid & 4095;                      // lanes adjacent in w -> coalesced
    int seg = gid >> 12;
    int b = col >> 9;
    int w = col & 511;
    int h0 = seg * SEG;
    const int* tp = &targ[b * HH * WW + w];

    unsigned d[NCLS], packed[NCLS];
#pragma unroll
    for (int c = 0; c < NCLS; ++c) { d[c] = DCAP; packed[c] = 0u; }

    int hstart = h0 - (int)DCAP; if (hstart < 0) hstart = 0;
    for (int hh = hstart; hh < h0 + SEG; ++hh) {
        int t = tp[hh * WW];
        int r8 = (hh - h0) * 8;
        bool live = (hh >= h0);
#pragma unroll
        for (int c = 0; c < NCLS; ++c) {
            d[c] = (t == c) ? 0u : umin32(d[c] + 1u, DCAP);
            if (live) packed[c] |= d[c] << r8;
        }
    }

    unsigned u[NCLS];
#pragma unroll
    for (int c = 0; c < NCLS; ++c) u[c] = DCAP;
    int hend = h0 + SEG - 1 + (int)DCAP; if (hend > HH - 1) hend = HH - 1;
    for (int hh = hend; hh >= h0 + SEG; --hh) {        // pre-roll below segment
        int t = tp[hh * WW];
#pragma unroll
        for (int c = 0; c < NCLS; ++c)
            u[c] = (t == c) ? 0u : umin32(u[c] + 1u, DCAP);
    }
    for (int hh = h0 + SEG - 1; hh >= h0; --hh) {      // merge + store once
        int t = tp[hh * WW];
        int r8 = (hh - h0) * 8;
#pragma unroll
        for (int c = 0; c < NCLS; ++c) {
            u[c] = (t == c) ? 0u : umin32(u[c] + 1u, DCAP);
            unsigned dv = (packed[c] >> r8) & 0xffu;
            vneg[((size_t)(b * NCLS + c) * HH + hh) * WW + w] =
                (unsigned char)umin32(dv, u[c]);
        }
    }
}

// ---------------------------------------------------------------------------
// Kernel B: per image row (b,h). v^2 staged as packed u16 pairs in LDS.
// Word k of class c holds (v2[2k-20], v2[2k-19]); k = 0..275 covers w=-20..531.
// Thread t owns pixels (2t, 2t+1); reads words t..t+20.
// Packed min-plus: p0 accumulates pixel0's even(lo)/odd(hi) taps,
// p1 pixel1's. Spurious d=+-21 taps saturate at the 400 cap.
// ---------------------------------------------------------------------------
#define LW 276

__global__ __launch_bounds__(256)
void kB_main(const float* __restrict__ logits, const int* __restrict__ targ,
             const unsigned char* __restrict__ vneg,
             unsigned long long* __restrict__ acc) {
    __shared__ unsigned int lds32[NCLS * LW];
    __shared__ float wsum[4];
    int bh = blockIdx.x;      // 0..B*H-1
    int b = bh >> 8;
    int h = bh & 255;
    int tid = threadIdx.x;

    // halo words: (441,441) == INF after the 400 cap
    const unsigned HALO = 441u | (441u << 16);
    for (int i = tid; i < NCLS * 20; i += 256) {
        int c = i / 20, k = i % 20;
        int idx = (k < 10) ? k : (266 + k - 10);
        lds32[c * LW + idx] = HALO;
    }
    // stage: read 4 u8 vertical distances, square, pack as 2 u16-pair words
    const unsigned int* vn32 = (const unsigned int*)vneg;
    for (int i = tid; i < NCLS * (WW / 4); i += 256) {
        int c = i >> 7;
        int w4 = i & 127;
        unsigned v4 = vn32[((size_t)(b * NCLS + c) * HH + h) * (WW / 4) + w4];
        unsigned v0 = v4 & 0xffu, v1 = (v4 >> 8) & 0xffu;
        unsigned v2 = (v4 >> 16) & 0xffu, v3 = (v4 >> 24) & 0xffu;
        unsigned p01 = (v0 * v0) | ((v1 * v1) << 16);
        unsigned p23 = (v2 * v2) | ((v3 * v3) << 16);
        int idx = c * LW + 10 + 2 * w4;
        lds32[idx] = p01;
        lds32[idx + 1] = p23;
    }
    __syncthreads();

    int w0 = tid * 2;
    int t0 = targ[(b * HH + h) * WW + w0];
    int t1 = targ[(b * HH + h) * WW + w0 + 1];

    float num0 = 0.f, num1 = 0.f, den0 = 0.f, den1 = 0.f;
    float et0 = 0.f, et1 = 0.f;
    unsigned m2_0 = 1u << 30, m2_1 = 1u << 30;
    const unsigned* lbase = lds32 + tid;

#pragma unroll 1
    for (int c = 0; c < NCLS; ++c) {
        const unsigned* lp = lbase + c * LW;
        u16x2 p0 = {0xFFFF, 0xFFFF};
        u16x2 p1 = {0xFFFF, 0xFFFF};
#pragma unroll
        for (int m = 0; m <= 20; ++m) {
            u16x2 wv = __builtin_bit_cast(u16x2, lp[m]);
            u16x2 k1 = {(unsigned short)((2 * m - 20) * (2 * m - 20)),
                        (unsigned short)((2 * m - 19) * (2 * m - 19))};
            u16x2 k2 = {(unsigned short)((2 * m - 21) * (2 * m - 21)),
                        (unsigned short)((2 * m - 20) * (2 * m - 20))};
            p0 = __builtin_elementwise_min(p0, (u16x2)(wv + k1));
            p1 = __builtin_elementwise_min(p1, (u16x2)(wv + k2));
        }
        unsigned nd0 = umin32((unsigned)p0.x, (unsigned)p0.y);
        unsigned nd1 = umin32((unsigned)p1.x, (unsigned)p1.y);

        float2 l2 = *(const float2*)&logits[(((size_t)b * NCLS + c) * HH + h) * WW + w0];
        float e0 = __expf(l2.x), e1 = __expf(l2.y);
        den0 += e0; den1 += e1;
        bool is0 = (c == t0), is1 = (c == t1);
        float s0 = fsqrt_fast((float)umin32(nd0, CAP2));
        float s1 = fsqrt_fast((float)umin32(nd1, CAP2));
        num0 += is0 ? 0.f : e0 * s0;
        num1 += is1 ? 0.f : e1 * s1;
        et0 = is0 ? e0 : et0;
        et1 = is1 ? e1 : et1;
        m2_0 = umin32(m2_0, is0 ? (1u << 30) : nd0);
        m2_1 = umin32(m2_1, is1 ? (1u << 30) : nd1);
    }
    num0 -= et0 * fsqrt_fast((float)umin32(m2_0, CAP2));
    num1 -= et1 * fsqrt_fast((float)umin32(m2_1, CAP2));

    float v = num0 / den0 + num1 / den1;   // /20 folded into final scale
#pragma unroll
    for (int off = 32; off >= 1; off >>= 1) v += __shfl_down(v, off);
    int lane = tid & 63, wid = tid >> 6;
    if (lane == 0) wsum[wid] = v;
    __syncthreads();
    if (tid == 0) {
        float s = wsum[0] + wsum[1] + wsum[2] + wsum[3];
        // fixed-point 2^36 with /20 folded in; integer atomic => deterministic
        double q = (double)s * (68719476736.0 / 20.0);
        long long iv = (long long)q;
        atomicAdd(acc, (unsigned long long)iv);
    }
}

__global__ void kC_final(const unsigned long long* __restrict__ acc,
                         float* __restrict__ out) {
    long long iv = (long long)*acc;
    double v = (double)iv / 68719476736.0;
    out[0] = (float)(v / (double)((size_t)BB * HH * WW));
}

extern "C" void kernel_launch(void* const* d_in, const int* in_sizes, int n_in,
                              void* d_out, int out_size, void* d_ws, size_t ws_size,
                              hipStream_t stream) {
    const float* logits = (const float*)d_in[0];
    const int* targ = (const int*)d_in[1];
    unsigned char* wsb = (unsigned char*)d_ws;
    unsigned long long* acc = (unsigned long long*)wsb;       // [0,8)
    unsigned char* vneg = wsb + 64;                           // 19.9 MB u8

    (void)hipMemsetAsync(d_ws, 0, 64, stream);
    kA_vert<<<1024, 256, 0, stream>>>(targ, vneg);            // 262144 threads
    kB_main<<<BB * HH, 256, 0, stream>>>(logits, targ, vneg, acc);
    kC_final<<<1, 1, 0, stream>>>(acc, (float*)d_out);
}

// Round 4
// 76.883 us; speedup vs baseline: 1.7581x; 1.2222x over previous
//
#include <hip/hip_runtime.h>
#include <hip/hip_bf16.h>
#include <math.h>

// logits [8,19,256,512] f32, targets [8,256,512] int32
// R=20 truncated EDT, loss = mean_b sum_c mean_hw probs*sdf
#define NCLS 19
#define BB   8
#define HH   256
#define WW   512
#define CAP2 400u     // R^2; any d >= 21 squares past this and is capped
#define SEG  8        // rows per kA segment

static __device__ __forceinline__ unsigned umin32(unsigned a, unsigned b) { return a < b ? a : b; }
static __device__ __forceinline__ float fsqrt_fast(float x) { return __builtin_amdgcn_sqrtf(x); }

static __device__ __forceinline__ unsigned pk_add_u16(unsigned a, unsigned b) {
    unsigned d;
    asm("v_pk_add_u16 %0, %1, %2" : "=v"(d) : "v"(a), "v"(b));
    return d;
}
static __device__ __forceinline__ unsigned pk_min_u16(unsigned a, unsigned b) {
    unsigned d;
    asm("v_pk_min_u16 %0, %1, %2" : "=v"(d) : "v"(a), "v"(b));
    return d;
}

// ---------------------------------------------------------------------------
// Kernel A: vertical pass. vneg[b][c][h][w] = min |dh| with targ[h+dh][w]==c,
// UNcapped (<=~50; kB's 400 cap on squares makes it equivalent to capping).
// 8-row segments; STATIC 29-iter scans (sentinel t=-1 out of range) so the
// compiler fully unrolls and hoists the row loads. No global RMW.
// ---------------------------------------------------------------------------
__global__ __launch_bounds__(256)
void kA_vert(const int* __restrict__ targ, unsigned char* __restrict__ vneg) {
    int gid = blockIdx.x * 256 + threadIdx.x;  // 4096 cols * 32 segs = 131072
    int col = gid & 4095;                      // lanes adjacent in w -> coalesced
    int seg = gid >> 12;                       // uniform within block
    int b = col >> 9;
    int w = col & 511;
    int h0 = seg * SEG;
    const int* tp = &targ[b * HH * WW + w];

    // down scan: rows h0-21 .. h0+7 (29 static iters)
    unsigned d[NCLS];
    unsigned pk[NCLS][2];   // 8 rows of u8 distances per class
#pragma unroll
    for (int c = 0; c < NCLS; ++c) { d[c] = 21u; pk[c][0] = 0u; pk[c][1] = 0u; }
#pragma unroll
    for (int k = 0; k < 21 + SEG; ++k) {
        int hh = h0 - 21 + k;
        int t = -1;
        if (hh >= 0) t = tp[hh * WW];          // uniform branch (seg 0..2 only)
#pragma unroll
        for (int c = 0; c < NCLS; ++c)
            d[c] = (t == c) ? 0u : d[c] + 1u;
        if (k >= 21) {
            int r = k - 21;
#pragma unroll
            for (int c = 0; c < NCLS; ++c)
                pk[c][r >> 2] |= d[c] << ((r & 3) * 8);
        }
    }

    // up scan: rows h0+28 .. h0 (29 static iters), merge + store once
    unsigned u[NCLS];
#pragma unroll
    for (int c = 0; c < NCLS; ++c) u[c] = 21u;
#pragma unroll
    for (int k = 0; k < 21 + SEG; ++k) {
        int hh = h0 + 21 + SEG - 1 - k;
        int t = -1;
        if (hh < HH) t = tp[hh * WW];          // uniform branch (bottom segs)
#pragma unroll
        for (int c = 0; c < NCLS; ++c)
            u[c] = (t == c) ? 0u : u[c] + 1u;
        if (k >= 21) {
            int r = 21 + SEG - 1 - k;          // 7..0
#pragma unroll
            for (int c = 0; c < NCLS; ++c) {
                unsigned dv = (pk[c][r >> 2] >> ((r & 3) * 8)) & 0xffu;
                vneg[((size_t)(b * NCLS + c) * HH + hh) * WW + w] =
                    (unsigned char)umin32(dv, u[c]);
            }
        }
    }
}

// ---------------------------------------------------------------------------
// Kernel B: per image row (b,h). v^2 staged as packed u16 pairs in LDS.
// Word k of class c holds (v2[2k-20], v2[2k-19]); k=0..275 covers w=-20..531.
// Thread t owns pixels (2t,2t+1), reads words t..t+20. Min-plus via
// v_pk_add_u16/v_pk_min_u16 inline asm, constants hoisted in registers.
// sdf identity: posdist(c) nonzero only at c==target, = second-min over classes.
// ---------------------------------------------------------------------------
#define LW 276

__global__ __launch_bounds__(256)
void kB_main(const float* __restrict__ logits, const int* __restrict__ targ,
             const unsigned char* __restrict__ vneg,
             unsigned long long* __restrict__ acc) {
    __shared__ unsigned int lds32[NCLS * LW];
    __shared__ float wsum[4];
    int bh = blockIdx.x;      // 0..B*H-1
    int b = bh >> 8;
    int h = bh & 255;
    int tid = threadIdx.x;

    // packed tap constants: K1 for even pixel (taps 2m-20, 2m-19),
    // K2 for odd pixel (taps 2m-21, 2m-20); |d|=21 taps saturate at the cap.
#define SQ(x) ((unsigned)((x) * (x)))
#define PK(a, bq) (SQ(a) | (SQ(bq) << 16))
    const unsigned K1r[21] = {
        PK(-20,-19), PK(-18,-17), PK(-16,-15), PK(-14,-13), PK(-12,-11),
        PK(-10,-9),  PK(-8,-7),   PK(-6,-5),   PK(-4,-3),   PK(-2,-1),
        PK(0,1),     PK(2,3),     PK(4,5),     PK(6,7),     PK(8,9),
        PK(10,11),   PK(12,13),   PK(14,15),   PK(16,17),   PK(18,19),
        PK(20,21) };
    const unsigned K2r[21] = {
        PK(-21,-20), PK(-19,-18), PK(-17,-16), PK(-15,-14), PK(-13,-12),
        PK(-11,-10), PK(-9,-8),   PK(-7,-6),   PK(-5,-4),   PK(-3,-2),
        PK(-1,0),    PK(1,2),     PK(3,4),     PK(5,6),     PK(7,8),
        PK(9,10),    PK(11,12),   PK(13,14),   PK(15,16),   PK(17,18),
        PK(19,20) };
#undef PK
#undef SQ

    // halo words: (441,441) >= cap, acts as INF
    const unsigned HALO = 441u | (441u << 16);
    for (int i = tid; i < NCLS * 20; i += 256) {
        int c = i / 20, k = i % 20;
        int idx = (k < 10) ? k : (266 + k - 10);
        lds32[c * LW + idx] = HALO;
    }
    // stage: read 4 u8 vertical distances, square, pack as 2 u16-pair words
    const unsigned int* vn32 = (const unsigned int*)vneg;
    for (int i = tid; i < NCLS * (WW / 4); i += 256) {
        int c = i >> 7;
        int w4 = i & 127;
        unsigned v4 = vn32[((size_t)(b * NCLS + c) * HH + h) * (WW / 4) + w4];
        unsigned v0 = v4 & 0xffu, v1 = (v4 >> 8) & 0xffu;
        unsigned v2 = (v4 >> 16) & 0xffu, v3 = (v4 >> 24) & 0xffu;
        unsigned p01 = (v0 * v0) | ((v1 * v1) << 16);
        unsigned p23 = (v2 * v2) | ((v3 * v3) << 16);
        int idx = c * LW + 10 + 2 * w4;
        lds32[idx] = p01;
        lds32[idx + 1] = p23;
    }
    __syncthreads();

    int w0 = tid * 2;
    int t0 = targ[(b * HH + h) * WW + w0];
    int t1 = targ[(b * HH + h) * WW + w0 + 1];

    float num0 = 0.f, num1 = 0.f, den0 = 0.f, den1 = 0.f;
    float et0 = 0.f, et1 = 0.f;
    unsigned m2_0 = 1u << 30, m2_1 = 1u << 30;
    const unsigned* lbase = lds32 + tid;

    for (int c = 0; c < NCLS; ++c) {
        const unsigned* lp = lbase + c * LW;
        unsigned p0 = 0xFFFFFFFFu, p1 = 0xFFFFFFFFu;
#pragma unroll
        for (int m = 0; m <= 20; ++m) {
            unsigned wv = lp[m];
            p0 = pk_min_u16(p0, pk_add_u16(wv, K1r[m]));
            p1 = pk_min_u16(p1, pk_add_u16(wv, K2r[m]));
        }
        unsigned nd0 = umin32(p0 & 0xFFFFu, p0 >> 16);
        unsigned nd1 = umin32(p1 & 0xFFFFu, p1 >> 16);

        float2 l2 = *(const float2*)&logits[(((size_t)b * NCLS + c) * HH + h) * WW + w0];
        float e0 = __expf(l2.x), e1 = __expf(l2.y);
        den0 += e0; den1 += e1;
        bool is0 = (c == t0), is1 = (c == t1);
        float s0 = fsqrt_fast((float)umin32(nd0, CAP2));
        float s1 = fsqrt_fast((float)umin32(nd1, CAP2));
        num0 += is0 ? 0.f : e0 * s0;
        num1 += is1 ? 0.f : e1 * s1;
        et0 = is0 ? e0 : et0;
        et1 = is1 ? e1 : et1;
        m2_0 = umin32(m2_0, is0 ? (1u << 30) : nd0);
        m2_1 = umin32(m2_1, is1 ? (1u << 30) : nd1);
    }
    num0 -= et0 * fsqrt_fast((float)umin32(m2_0, CAP2));
    num1 -= et1 * fsqrt_fast((float)umin32(m2_1, CAP2));

    float v = num0 / den0 + num1 / den1;   // /20 folded into final scale
#pragma unroll
    for (int off = 32; off >= 1; off >>= 1) v += __shfl_down(v, off);
    int lane = tid & 63, wid = tid >> 6;
    if (lane == 0) wsum[wid] = v;
    __syncthreads();
    if (tid == 0) {
        float s = wsum[0] + wsum[1] + wsum[2] + wsum[3];
        // fixed-point 2^36 with /20 folded in; integer atomic => deterministic
        double q = (double)s * (68719476736.0 / 20.0);
        long long iv = (long long)q;
        atomicAdd(acc, (unsigned long long)iv);
    }
}

__global__ void kC_final(const unsigned long long* __restrict__ acc,
                         float* __restrict__ out) {
    long long iv = (long long)*acc;
    double v = (double)iv / 68719476736.0;
    out[0] = (float)(v / (double)((size_t)BB * HH * WW));
}

extern "C" void kernel_launch(void* const* d_in, const int* in_sizes, int n_in,
                              void* d_out, int out_size, void* d_ws, size_t ws_size,
                              hipStream_t stream) {
    const float* logits = (const float*)d_in[0];
    const int* targ = (const int*)d_in[1];
    unsigned char* wsb = (unsigned char*)d_ws;
    unsigned long long* acc = (unsigned long long*)wsb;       // [0,8)
    unsigned char* vneg = wsb + 64;                           // 19.9 MB u8

    (void)hipMemsetAsync(d_ws, 0, 64, stream);
    kA_vert<<<512, 256, 0, stream>>>(targ, vneg);             // 131072 threads
    kB_main<<<BB * HH, 256, 0, stream>>>(logits, targ, vneg, acc);
    kC_final<<<1, 1, 0, stream>>>(acc, (float*)d_out);
}